// Round 11
// baseline (882.490 us; speedup 1.0000x reference)
//
#include <hip/hip_runtime.h>
#include <hip/hip_bf16.h>

// CombineGraph forward. B=128,S=50,D=128,NODES=40000,SAMPLE=12,NNEI=8,HOP=2.
// Round 11: kG = 832 threads (13 waves), ONE UNIT PER WAVE, ALL CONCURRENT.
// Serial depth per block: 1 unit + phase B + phase C (3 barriers). Final
// W3b matvec via MFMA (p3b frags) instead of 838MB of redundant L2 reads.

#define B 128
#define S 50
#define D 128
#define SAMPLE 12
#define NNEI 8
#define NODES 40000
#define NSC (NODES - 1)
#define LEAK 0.2f
#define TEMPV 0.5f
#define MUV 0.1f
#define NEG_BIG -3.0e38f

typedef const float* fpp;
typedef float* fpw;
typedef unsigned short u16;
typedef __attribute__((ext_vector_type(8))) short bfrag8;
typedef __attribute__((ext_vector_type(4))) float f32x4;

__device__ __forceinline__ float sigm(float x) { return 1.f / (1.f + __expf(-x)); }
__device__ __forceinline__ float tanh_f(float x) { return 1.f - 2.f / (__expf(2.f * x) + 1.f); }
__device__ __forceinline__ float leaky(float x) { return x >= 0.f ? x : LEAK * x; }
__device__ __forceinline__ u16 f2bf(float v) {
  __hip_bfloat16 h = __float2bfloat16(v);
  return *reinterpret_cast<u16*>(&h);
}

// ---------------------------------------------------------------------------
// KPREP4: all four weight tensors -> bf16 B-fragment order in one launch.
__global__ __launch_bounds__(256) void kprep4(fpp gw1, fpp gw3,
                                              u16* __restrict__ p1a,
                                              u16* __restrict__ p1b,
                                              u16* __restrict__ p3a,
                                              u16* __restrict__ p3b) {
  int i = blockIdx.x * 256 + threadIdx.x;
  fpp W; u16* dst; int KS;
  if (i < 16384)      { W = gw1;             dst = p1a; KS = 4; }
  else if (i < 32768) { W = gw1 + 129 * 128; dst = p1b; KS = 4; i -= 16384; }
  else if (i < 65536) { W = gw3;             dst = p3a; KS = 8; i -= 32768; }
  else                { W = gw3 + 256 * 128; dst = p3b; KS = 8; i -= 65536; }
  int e = i & 7;
  int lane = (i >> 3) & 63;
  int rest = i >> 9;
  int ks = rest % KS, nt = rest / KS;
  int k = ks * 32 + ((lane >> 4) << 3) + e;
  int n = (nt << 4) + (lane & 15);
  dst[i] = f2bf(W[(long)k * 128 + n]);
}

// ---------------------------------------------------------------------------
// K1: h = emb[inputs]; hf1/hf2 pools; attr gate. Block per (b,s), 128 thr.
__global__ __launch_bounds__(128) void k1_gather(
    const int* __restrict__ inputs, const int* __restrict__ as0,
    const int* __restrict__ as1, const int* __restrict__ ss0,
    const int* __restrict__ ss1, fpp emb, fpp attr_w,
    fpw h, fpw hf1, fpw hf2, float* __restrict__ mi, fpw xA, fpw mir) {
  int bs = blockIdx.x;
  int d = threadIdx.x;
  __shared__ float h_s[D], hf1_s[D];
  int inp = inputs[bs];
  float hv = emb[(long)inp * D + d];
  const int* lists[4] = {as0, as1, ss0, ss1};
  float p[4];
#pragma unroll
  for (int l = 0; l < 4; l++) {
    float sum = 0.f, cnt = 0.f;
    const int* L = lists[l] + (long)bs * NNEI;
#pragma unroll
    for (int n = 0; n < NNEI; n++) {
      int idx = L[n];
      if (idx != 0) { sum += emb[(long)idx * D + d]; cnt += 1.f; }
    }
    p[l] = sum / (cnt + 1e-8f);
  }
  float hf1v = 0.5f * (p[0] + p[1]);
  float hf2v = 0.5f * (p[2] + p[3]);
  h_s[d] = hv;
  hf1_s[d] = hf1v;
  __syncthreads();
  float acc = 0.f;
  for (int k = 0; k < D; k++)
    acc += h_s[k] * attr_w[(long)k * D + d] + hf1_s[k] * attr_w[(long)(D + k) * D + d];
  float g = sigm(acc);
  float hfv = g * hv + (1.f - g) * hf1v;
  long o = (long)bs * D + d;
  h[o] = hv; hf1[o] = hf1v; hf2[o] = hf2v; xA[o] = hv; mir[o] = hfv;
  if (d == 0) mi[bs] = (inp != 0) ? 1.f : 0.f;
}

// ---------------------------------------------------------------------------
// K2: sess[b,:] = sum_s emb[item[b,s]]*mi / sum_s mi
__global__ __launch_bounds__(128) void k2_sess(const int* __restrict__ inputs,
                                               const int* __restrict__ item,
                                               fpp emb, fpw sess) {
  int b = blockIdx.x;
  int d = threadIdx.x;
  float acc = 0.f, ms = 0.f;
  for (int s = 0; s < S; s++) {
    int inp = inputs[b * S + s];
    float m = (inp != 0) ? 1.f : 0.f;
    int it = item[b * S + s];
    acc += emb[(long)it * D + d] * m;
    ms += m;
  }
  sess[(long)b * D + d] = acc / ms;
}

// ---------------------------------------------------------------------------
// KG: 2-hop global branch, one block per (b,s), 832 threads = 13 waves.
// Wave u computes hop-0 unit u — all 13 CONCURRENT (no serial unit chain).
// Own-wave LDS staging -> MFMA needs no barrier. 3 block barriers total.
__global__ __launch_bounds__(832) void kG_global(
    const int* __restrict__ inputs, const int* __restrict__ adj_all,
    fpp num, fpp emb, fpp sess,
    fpp W1a, fpp W2a, fpp W1b, fpp W2b,
    const u16* __restrict__ p1a, const u16* __restrict__ p1b,
    const u16* __restrict__ p3a, const u16* __restrict__ p3b,
    fpw hg) {
  int bs = blockIdx.x;
  int b = bs / S;
  int d = threadIdx.x;      // 0..831
  int lane = d & 63;
  int v = d >> 6;           // wave 0..12
  int q = lane >> 4;
  int mrow = lane & 15;

  __shared__ __align__(16) u16 nvs_l[13][16 * 136];  // per-wave A stage
  __shared__ __align__(16) u16 svagg_l[16 * 264];    // [sv|agg] bf16
  __shared__ __align__(16) float ev_l[13 * 128];
  __shared__ int n1_l[SAMPLE];

  // zero own A-stage pad rows (cols 0..127 suffice; frags read <128)
#pragma unroll
  for (int r = 12; r < 16; r++) {
    nvs_l[v][r * 136 + lane] = 0;
    nvs_l[v][r * 136 + 64 + lane] = 0;
  }
  int src0 = __builtin_amdgcn_readfirstlane(inputs[bs]);
  if (v == 0) {
    // svagg pad rows 13..15 (cols 0..255)
#pragma unroll
    for (int r = 13; r < 16; r++) {
      svagg_l[r * 264 + lane] = 0;
      svagg_l[r * 264 + 64 + lane] = 0;
      svagg_l[r * 264 + 128 + lane] = 0;
      svagg_l[r * 264 + 192 + lane] = 0;
    }
    if (lane < SAMPLE) n1_l[lane] = adj_all[(long)src0 * SAMPLE + lane];
  }
  float sess0 = sess[(long)b * D + lane];
  float sess1 = sess[(long)b * D + 64 + lane];
  float w2A[8], wlA[8];
#pragma unroll
  for (int nt = 0; nt < 8; nt++) {
    int col = nt * 16 + mrow;
    w2A[nt] = W2a[col];
    wlA[nt] = W1a[(long)D * D + col];
  }
  __syncthreads();  // n1_l + pads visible

  // ---- Phase A: unit v on wave v (13 concurrent) ------------------------
  {
    int u = v;
    int src = (u == 0) ? src0 : __builtin_amdgcn_readfirstlane(n1_l[u - 1]);
    float r0[SAMPLE], r1[SAMPLE];
#pragma unroll
    for (int j = 0; j < SAMPLE; j++) {
      long base = (long)__builtin_amdgcn_readfirstlane(adj_all[(long)src * SAMPLE + j]) * D;
      r0[j] = emb[base + lane];
      r1[j] = emb[base + 64 + lane];
    }
    float nwv = (lane < SAMPLE) ? num[(long)src * SAMPLE + lane] : 0.f;
    // sv row of this unit
    svagg_l[u * 264 + lane] = f2bf(emb[(long)src * D + lane]);
    svagg_l[u * 264 + 64 + lane] = f2bf(emb[(long)src * D + 64 + lane]);
    u16* nvs = nvs_l[v];
#pragma unroll
    for (int j = 0; j < SAMPLE; j++) {
      nvs[j * 136 + lane] = f2bf(r0[j] * sess0);
      nvs[j * 136 + 64 + lane] = f2bf(r1[j] * sess1);
    }
    f32x4 acc[8];
#pragma unroll
    for (int nt = 0; nt < 8; nt++) acc[nt] = (f32x4){0.f, 0.f, 0.f, 0.f};
#pragma unroll
    for (int ks = 0; ks < 4; ks++) {
      bfrag8 a = *(const bfrag8*)(nvs + mrow * 136 + q * 8 + ks * 32);
#pragma unroll
      for (int nt = 0; nt < 8; nt++) {
        bfrag8 bb = *(const bfrag8*)(p1a + (nt * 4 + ks) * 512 + lane * 8);
        acc[nt] = __builtin_amdgcn_mfma_f32_16x16x32_bf16(a, bb, acc[nt], 0, 0, 0);
      }
    }
    float nwr[4];
#pragma unroll
    for (int i2 = 0; i2 < 4; i2++) nwr[i2] = __shfl(nwv, q * 4 + i2, 64);
    float lp[4] = {0.f, 0.f, 0.f, 0.f};
#pragma unroll
    for (int nt = 0; nt < 8; nt++)
#pragma unroll
      for (int i2 = 0; i2 < 4; i2++)
        lp[i2] += leaky(acc[nt][i2] + nwr[i2] * wlA[nt]) * w2A[nt];
#pragma unroll
    for (int off = 1; off <= 8; off <<= 1)
#pragma unroll
      for (int i2 = 0; i2 < 4; i2++) lp[i2] += __shfl_xor(lp[i2], off, 64);
    float lg[SAMPLE];
#pragma unroll
    for (int r = 0; r < SAMPLE; r++) lg[r] = __shfl(lp[r & 3], (r >> 2) * 16, 64);
    float mx = lg[0];
#pragma unroll
    for (int j = 1; j < SAMPLE; j++) mx = fmaxf(mx, lg[j]);
    float se = 0.f;
#pragma unroll
    for (int j = 0; j < SAMPLE; j++) { lg[j] = __expf(lg[j] - mx); se += lg[j]; }
    float inv = 1.f / se;
    float a0 = 0.f, a1 = 0.f;
#pragma unroll
    for (int j = 0; j < SAMPLE; j++) {
      float al = lg[j] * inv;
      a0 += al * r0[j];
      a1 += al * r1[j];
    }
    svagg_l[u * 264 + 128 + lane] = f2bf(a0);
    svagg_l[u * 264 + 128 + 64 + lane] = f2bf(a1);
  }
  __syncthreads();  // all svagg rows settled

  // ---- Phase B: [sv|agg] (13x256) @ W3a -> ev, waves 0..3 x 2 ntiles ----
  if (v < 4) {
    f32x4 accB[2];
#pragma unroll
    for (int nt = 0; nt < 2; nt++) accB[nt] = (f32x4){0.f, 0.f, 0.f, 0.f};
#pragma unroll
    for (int ks = 0; ks < 8; ks++) {
      bfrag8 a = *(const bfrag8*)(svagg_l + mrow * 264 + q * 8 + ks * 32);
#pragma unroll
      for (int nt = 0; nt < 2; nt++) {
        bfrag8 bb = *(const bfrag8*)(p3a + ((v * 2 + nt) * 8 + ks) * 512 + lane * 8);
        accB[nt] = __builtin_amdgcn_mfma_f32_16x16x32_bf16(a, bb, accB[nt], 0, 0, 0);
      }
    }
#pragma unroll
    for (int nt = 0; nt < 2; nt++) {
      int col = (v * 2 + nt) * 16 + mrow;
#pragma unroll
      for (int i2 = 0; i2 < 4; i2++) {
        int u2 = q * 4 + i2;
        if (u2 < 13) ev_l[u2 * 128 + col] = tanh_f(accB[nt][i2]);
      }
    }
  }
  __syncthreads();  // ev ready; svagg reads done

  // ---- Phase C: hop-1 unit on wave 0; waves 1..12 zero svagg rows -------
  if (v == 0) {
    float e0[SAMPLE], e1[SAMPLE];
    float nwc = (lane < SAMPLE) ? num[(long)src0 * SAMPLE + lane] : 0.f;
    u16* nvs = nvs_l[0];
#pragma unroll
    for (int j = 0; j < SAMPLE; j++) {
      e0[j] = ev_l[(1 + j) * 128 + lane];
      e1[j] = ev_l[(1 + j) * 128 + 64 + lane];
      nvs[j * 136 + lane] = f2bf(e0[j] * sess0);
      nvs[j * 136 + 64 + lane] = f2bf(e1[j] * sess1);
    }
    float w2Bc[8], wlBc[8];
#pragma unroll
    for (int nt = 0; nt < 8; nt++) {
      int col = nt * 16 + mrow;
      w2Bc[nt] = W2b[col];
      wlBc[nt] = W1b[(long)D * D + col];
    }
    f32x4 acc[8];
#pragma unroll
    for (int nt = 0; nt < 8; nt++) acc[nt] = (f32x4){0.f, 0.f, 0.f, 0.f};
#pragma unroll
    for (int ks = 0; ks < 4; ks++) {
      bfrag8 a = *(const bfrag8*)(nvs + mrow * 136 + q * 8 + ks * 32);
#pragma unroll
      for (int nt = 0; nt < 8; nt++) {
        bfrag8 bb = *(const bfrag8*)(p1b + (nt * 4 + ks) * 512 + lane * 8);
        acc[nt] = __builtin_amdgcn_mfma_f32_16x16x32_bf16(a, bb, acc[nt], 0, 0, 0);
      }
    }
    float nwr[4];
#pragma unroll
    for (int i2 = 0; i2 < 4; i2++) nwr[i2] = __shfl(nwc, q * 4 + i2, 64);
    float lp[4] = {0.f, 0.f, 0.f, 0.f};
#pragma unroll
    for (int nt = 0; nt < 8; nt++)
#pragma unroll
      for (int i2 = 0; i2 < 4; i2++)
        lp[i2] += leaky(acc[nt][i2] + nwr[i2] * wlBc[nt]) * w2Bc[nt];
#pragma unroll
    for (int off = 1; off <= 8; off <<= 1)
#pragma unroll
      for (int i2 = 0; i2 < 4; i2++) lp[i2] += __shfl_xor(lp[i2], off, 64);
    float lg[SAMPLE];
#pragma unroll
    for (int r = 0; r < SAMPLE; r++) lg[r] = __shfl(lp[r & 3], (r >> 2) * 16, 64);
    float mx = lg[0];
#pragma unroll
    for (int j = 1; j < SAMPLE; j++) mx = fmaxf(mx, lg[j]);
    float se = 0.f;
#pragma unroll
    for (int j = 0; j < SAMPLE; j++) { lg[j] = __expf(lg[j] - mx); se += lg[j]; }
    float inv = 1.f / se;
    float a0 = 0.f, a1 = 0.f;
#pragma unroll
    for (int j = 0; j < SAMPLE; j++) {
      float al = lg[j] * inv;
      a0 += al * e0[j];
      a1 += al * e1[j];
    }
    // row 0 of the final A-tile: [ev0 | agg1]
    svagg_l[lane] = f2bf(ev_l[lane]);
    svagg_l[64 + lane] = f2bf(ev_l[64 + lane]);
    svagg_l[128 + lane] = f2bf(a0);
    svagg_l[192 + lane] = f2bf(a1);
  } else {
    // zero rows 1..12 of the final A-tile (svagg reads completed pre-barrier)
    svagg_l[v * 264 + lane] = 0;
    svagg_l[v * 264 + 64 + lane] = 0;
    svagg_l[v * 264 + 128 + lane] = 0;
    svagg_l[v * 264 + 192 + lane] = 0;
  }
  __syncthreads();

  // ---- Final: [ev0|agg1] (1x256) @ W3b via MFMA (p3b), waves 0..3 -------
  if (v < 4) {
    f32x4 accF[2];
#pragma unroll
    for (int nt = 0; nt < 2; nt++) accF[nt] = (f32x4){0.f, 0.f, 0.f, 0.f};
#pragma unroll
    for (int ks = 0; ks < 8; ks++) {
      bfrag8 a = *(const bfrag8*)(svagg_l + mrow * 264 + q * 8 + ks * 32);
#pragma unroll
      for (int nt = 0; nt < 2; nt++) {
        bfrag8 bb = *(const bfrag8*)(p3b + ((v * 2 + nt) * 8 + ks) * 512 + lane * 8);
        accF[nt] = __builtin_amdgcn_mfma_f32_16x16x32_bf16(a, bb, accF[nt], 0, 0, 0);
      }
    }
    if (q == 0) {  // C row 0 = our single real row
#pragma unroll
      for (int nt = 0; nt < 2; nt++) {
        int col = (v * 2 + nt) * 16 + mrow;
        hg[(long)bs * D + col] = tanh_f(accF[nt][0]);
      }
    }
  }
}

// ---------------------------------------------------------------------------
// K5AB: fused local-attention + mirror gate (+highway on fin=1). 128 thr.
__global__ __launch_bounds__(128) void k5ab(fpp x, const int* __restrict__ adj,
                                            fpp a_loc, fpp w1, fpp w2,
                                            fpw xout, fpw mir,
                                            fpp hw, fpp h, fpw x_dot,
                                            float* __restrict__ h_local,
                                            int fin) {
  int b = blockIdx.x / S;
  int row = blockIdx.x % S;
  int tid = threadIdx.x;
  __shared__ float xi_s[D];
  __shared__ float ak_s[4][D];
  __shared__ float alpha_s[S];
  __shared__ float part_s[4][2][64];
  long idx = ((long)b * S + row) * D + tid;
  xi_s[tid] = x[idx];
#pragma unroll
  for (int k = 0; k < 4; k++) ak_s[k][tid] = a_loc[(long)k * D + tid];
  __syncthreads();
  {
    int j = tid & 63, hf = tid >> 6;
    float a0 = 0.f, a1 = 0.f, a2 = 0.f, a3 = 0.f;
    if (j < S) {
      const float* xj = x + ((long)b * S + j) * D + hf * 64;
      int off = hf * 64;
      for (int dd = 0; dd < 64; dd++) {
        float prod = xi_s[off + dd] * xj[dd];
        a0 += prod * ak_s[0][off + dd];
        a1 += prod * ak_s[1][off + dd];
        a2 += prod * ak_s[2][off + dd];
        a3 += prod * ak_s[3][off + dd];
      }
    }
    part_s[0][hf][j] = a0; part_s[1][hf][j] = a1;
    part_s[2][hf][j] = a2; part_s[3][hf][j] = a3;
  }
  __syncthreads();
  if (tid < 64) {
    int j = tid;
    float att;
    if (j < S) {
      float acc0 = part_s[0][0][j] + part_s[0][1][j];
      float acc1 = part_s[1][0][j] + part_s[1][1][j];
      float acc2 = part_s[2][0][j] + part_s[2][1][j];
      float acc3 = part_s[3][0][j] + part_s[3][1][j];
      int av = adj[((long)b * S + row) * S + j];
      att = -9e15f;  // reference's own sentinel
      if (av == 1) att = leaky(acc0);
      else if (av == 2) att = leaky(acc1);
      else if (av == 3) att = leaky(acc2);
      else if (av == 4) att = leaky(acc3);
    } else {
      att = NEG_BIG;
    }
    float mx = att;
#pragma unroll
    for (int o = 32; o > 0; o >>= 1) mx = fmaxf(mx, __shfl_xor(mx, o, 64));
    float e = __expf(att - mx);
    float ssum = e;
#pragma unroll
    for (int o = 32; o > 0; o >>= 1) ssum += __shfl_xor(ssum, o, 64);
    if (j < S) alpha_s[j] = e / ssum;
  }
  __syncthreads();
  float xn = 0.f;
  for (int j = 0; j < S; j++) xn += alpha_s[j] * x[((long)b * S + j) * D + tid];
  float mv = mir[idx];
  ak_s[0][tid] = xn;
  ak_s[1][tid] = mv;
  __syncthreads();
  float a2m = 0.f;
  for (int k = 0; k < D; k++)
    a2m += ak_s[0][k] * w1[(long)k * D + tid] + ak_s[1][k] * w2[(long)k * D + tid];
  float g = sigm(a2m);
  float xg = g * xn + (1.f - g) * mv;
  if (!fin) {
    xout[idx] = xg;
    mir[idx] = g * mv + (1.f - g) * xn;
    return;
  }
  float hv = h[idx];
  ak_s[2][tid] = hv;
  ak_s[3][tid] = xg;
  __syncthreads();
  float a3m = 0.f;
  for (int k = 0; k < D; k++)
    a3m += ak_s[2][k] * hw[(long)k * D + tid] + ak_s[3][k] * hw[(long)(D + k) * D + tid];
  float gh = sigm(a3m);
  float xd = gh * hv + (1.f - gh) * xg;
  x_dot[idx] = xd;
  if (row == S - 1) h_local[(long)b * D + tid] = xd;
}

// ---------------------------------------------------------------------------
// K7: simi loss. Block per (b,i), 128 threads (split-dot). atomicAdd to ws.
__global__ __launch_bounds__(128) void k7_simi(fpp hf1, fpp hf2,
                                               const int* __restrict__ simi_mask,
                                               float* __restrict__ loss) {
  int b = blockIdx.x / S;
  int i = blockIdx.x % S;
  int t = threadIdx.x;
  __shared__ float hi_s[D];
  __shared__ float part_s[2][64];
  hi_s[t] = hf1[((long)b * S + i) * D + t];
  __syncthreads();
  {
    int j = t & 63, hf = t >> 6;
    float acc = 0.f;
    if (j < S) {
      const float* r = hf2 + ((long)b * S + j) * D + hf * 64;
      int off = hf * 64;
      for (int dd = 0; dd < 64; dd++) acc += hi_s[off + dd] * r[dd];
    }
    part_s[hf][j] = acc;
  }
  __syncthreads();
  if (t < 64) {
    int j = t;
    float sim = (j < S) ? (part_s[0][j] + part_s[1][j]) * (1.0f / TEMPV) : NEG_BIG;
    float mx = sim;
#pragma unroll
    for (int o = 32; o > 0; o >>= 1) mx = fmaxf(mx, __shfl_xor(mx, o, 64));
    float e = __expf(sim - mx);
    float ssum = e;
#pragma unroll
    for (int o = 32; o > 0; o >>= 1) ssum += __shfl_xor(ssum, o, 64);
    float contrib = 0.f;
    if (j < S) {
      float p = e / ssum;
      float l = -__logf(p + 1e-8f);
      if (simi_mask[((long)b * S + i) * S + j] == 1) contrib = l;
    }
#pragma unroll
    for (int o = 32; o > 0; o >>= 1) contrib += __shfl_xor(contrib, o, 64);
    if (j == 0) atomicAdd(loss, contrib);
  }
}

// ---------------------------------------------------------------------------
// K8: GLU epilogue per batch, 512 threads = 4 s-groups (serial 50 -> 13).
__global__ __launch_bounds__(512) void k8_glu(
    fpp hg, fpp x_dot, fpp pos, fpp h_local, const float* __restrict__ mi,
    fpp glu1, fpp glu2, fpp glu4, fpp glu4b, fpp w_s, fpp gate_w, fpw zh) {
  int b = blockIdx.x;
  int t = threadIdx.x;
  int d = t & 127;
  int g = t >> 7;   // s-group 0..3
  __shared__ float hs_s[D], hl_s[D];
  __shared__ float hp_g[4][D], part[4][D], zg_g[4][D];
  __shared__ float red2[4][2];
  float msf = 0.f;
  for (int s = 0; s < S; s++) msf += mi[b * S + s];
  float hsacc = 0.f;
  for (int s = g * 13; s < min(S, g * 13 + 13); s++)
    hsacc += hg[((long)b * S + s) * D + d] * mi[b * S + s];
  part[g][d] = hsacc;
  if (g == 1) hl_s[d] = h_local[(long)b * D + d];
  __syncthreads();
  if (g == 0) hs_s[d] = (part[0][d] + part[1][d] + part[2][d] + part[3][d]) / msf;
  __syncthreads();
  float c = glu4b[d];
  for (int k = 0; k < D; k++)
    c += hs_s[k] * glu2[(long)k * D + d] + hl_s[k] * glu4[(long)k * D + d];
  float wsd = w_s[d];
  float zg = 0.f;
  for (int it = 0; it < 13; it++) {
    int s = g * 13 + it;
    bool act = s < S;
    float hp = 0.f;
    if (act) {
      hp = x_dot[((long)b * S + s) * D + d] + pos[(long)s * D + d];
      hp_g[g][d] = hp;
    }
    __syncthreads();
    if (act) {
      float acc = c;
      for (int k = 0; k < D; k++) acc += hp_g[g][k] * glu1[(long)k * D + d];
      float v = sigm(acc) * wsd;
#pragma unroll
      for (int o = 32; o > 0; o >>= 1) v += __shfl_down(v, o, 64);
      if ((t & 63) == 0) red2[g][(t >> 6) & 1] = v;
    }
    __syncthreads();
    if (act) {
      float beta = (red2[g][0] + red2[g][1]) * mi[b * S + s];
      zg += beta * hp;
    }
    __syncthreads();
  }
  zg_g[g][d] = zg;
  __syncthreads();
  if (g == 0) {
    float zgf = zg_g[0][d] + zg_g[1][d] + zg_g[2][d] + zg_g[3][d];
    hp_g[0][d] = zgf;
  }
  __syncthreads();
  if (g == 0) {
    float zgf = hp_g[0][d];
    float acc = 0.f;
    for (int k = 0; k < D; k++)
      acc += hp_g[0][k] * gate_w[(long)k * D + d] +
             hl_s[k] * gate_w[(long)(D + k) * D + d];
    float gf = sigm(acc) * MUV;
    zh[(long)b * D + d] = gf * hl_s[d] + (1.f - gf) * zgf;
  }
}

// ---------------------------------------------------------------------------
// K9: scores = zh(128x128) @ emb[1:]^T via bf16 MFMA. Block = 64 n-cols.
__global__ __launch_bounds__(256) void k9_scores(fpp zh, fpp emb, fpp loss,
                                                 float* __restrict__ out) {
  int t = threadIdx.x;
  if (blockIdx.x == 0 && t == 0) out[0] = loss[0] * (1.0f / (float)B);
  int lane = t & 63;
  int w = t >> 6;
  int q = lane >> 4;
  int mrow = lane & 15;
  long n = (long)blockIdx.x * 64 + w * 16 + mrow;
  bool valid = n < NSC;
  long nrow = valid ? (n + 1) : 1;
  bfrag8 bfr[4];
#pragma unroll
  for (int ks = 0; ks < 4; ks++) {
    const float* src = emb + nrow * D + ks * 32 + q * 8;
    float4 lo = *(const float4*)src;
    float4 hi = *(const float4*)(src + 4);
    bfrag8 bb;
    bb[0] = (short)f2bf(lo.x); bb[1] = (short)f2bf(lo.y);
    bb[2] = (short)f2bf(lo.z); bb[3] = (short)f2bf(lo.w);
    bb[4] = (short)f2bf(hi.x); bb[5] = (short)f2bf(hi.y);
    bb[6] = (short)f2bf(hi.z); bb[7] = (short)f2bf(hi.w);
    bfr[ks] = bb;
  }
#pragma unroll
  for (int mt = 0; mt < 8; mt++) {
    f32x4 acc = (f32x4){0.f, 0.f, 0.f, 0.f};
#pragma unroll
    for (int ks = 0; ks < 4; ks++) {
      const float* za = zh + (long)(mt * 16 + mrow) * D + ks * 32 + q * 8;
      float4 lo = *(const float4*)za;
      float4 hi = *(const float4*)(za + 4);
      bfrag8 a;
      a[0] = (short)f2bf(lo.x); a[1] = (short)f2bf(lo.y);
      a[2] = (short)f2bf(lo.z); a[3] = (short)f2bf(lo.w);
      a[4] = (short)f2bf(hi.x); a[5] = (short)f2bf(hi.y);
      a[6] = (short)f2bf(hi.z); a[7] = (short)f2bf(hi.w);
      acc = __builtin_amdgcn_mfma_f32_16x16x32_bf16(a, bfr[ks], acc, 0, 0, 0);
    }
    if (valid) {
#pragma unroll
      for (int i = 0; i < 4; i++) {
        int m = mt * 16 + q * 4 + i;
        out[1 + (long)m * NSC + n] = acc[i];
      }
    }
  }
}

// ---------------------------------------------------------------------------
extern "C" void kernel_launch(void* const* d_in, const int* in_sizes, int n_in,
                              void* d_out, int out_size, void* d_ws, size_t ws_size,
                              hipStream_t stream) {
  (void)in_sizes; (void)n_in; (void)out_size; (void)ws_size;
  const int* inputs = (const int*)d_in[0];
  const int* adj = (const int*)d_in[1];
  const int* item = (const int*)d_in[2];
  const int* simi_mask = (const int*)d_in[3];
  const int* as0 = (const int*)d_in[4];
  const int* as1 = (const int*)d_in[5];
  const int* ss0 = (const int*)d_in[6];
  const int* ss1 = (const int*)d_in[7];
  // d_in[8]: last_item_mask — structurally [:, -1]; hardcoded in k5ab(fin).
  const int* adj_all = (const int*)d_in[9];
  fpp num = (fpp)d_in[10];
  fpp emb = (fpp)d_in[11];
  fpp pos = (fpp)d_in[12];
  fpp a_local = (fpp)d_in[13];
  fpp mir_w1 = (fpp)d_in[14];
  fpp mir_w2 = (fpp)d_in[15];
  fpp gw1 = (fpp)d_in[16];
  fpp gw2 = (fpp)d_in[17];
  fpp gw3 = (fpp)d_in[18];
  fpp attr_w = (fpp)d_in[19];
  fpp highway_w = (fpp)d_in[20];
  fpp glu1 = (fpp)d_in[21];
  fpp glu2 = (fpp)d_in[22];
  fpp glu4 = (fpp)d_in[23];
  fpp glu4b = (fpp)d_in[24];
  fpp w_s = (fpp)d_in[25];
  fpp gate_w = (fpp)d_in[26];

  // fp32 scratch inside d_out: 6 * 819200 = 4,915,200 elts <= 5,119,873.
  float* ob = (float*)d_out;
  constexpr long BSD_ = (long)B * S * D;  // 819200
  fpw s_h = ob + 0 * BSD_;
  fpw s_hf1 = ob + 1 * BSD_;  // later x_dot
  fpw s_hf2 = ob + 2 * BSD_;  // later h_global
  fpw s_mir = ob + 3 * BSD_;
  fpw s_xA = ob + 4 * BSD_;
  fpw s_xB = ob + 5 * BSD_;

  // small fp32 state in d_ws, loss at ws[0]; prepped weights after 72000 floats.
  float* ws = (float*)d_ws;
  float* w_loss = ws + 0;
  float* w_mi = ws + 16;                // B*S
  float* w_sess = w_mi + (long)B * S;   // B*D
  float* w_hl = w_sess + (long)B * D;   // B*D
  float* w_zh = w_hl + (long)B * D;     // B*D
  u16* p1a = (u16*)(ws + 72000);          // 16384 u16
  u16* p1b = (u16*)(ws + 72000 + 8192);   // 16384 u16
  u16* p3a = (u16*)(ws + 72000 + 16384);  // 32768 u16
  u16* p3b = (u16*)(ws + 72000 + 32768);  // 32768 u16

  hipMemsetAsync((void*)w_loss, 0, sizeof(float), stream);

  kprep4<<<384, 256, 0, stream>>>(gw1, gw3, p1a, p1b, p3a, p3b);
  k1_gather<<<B * S, 128, 0, stream>>>(inputs, as0, as1, ss0, ss1, emb, attr_w,
                                       s_h, s_hf1, s_hf2, w_mi, s_xA, s_mir);
  // k7 consumes hf1/hf2 before kG reuses the hf2 slot as h_global.
  k7_simi<<<B * S, 128, 0, stream>>>(s_hf1, s_hf2, simi_mask, w_loss);
  k2_sess<<<B, 128, 0, stream>>>(inputs, item, emb, w_sess);
  kG_global<<<B * S, 832, 0, stream>>>(inputs, adj_all, num, emb, w_sess,
                                       gw1, gw2, gw1 + 129 * 128, gw2 + 128,
                                       p1a, p1b, p3a, p3b,
                                       s_hf2 /* h_global */);
  k5ab<<<B * S, 128, 0, stream>>>(s_xA, adj, a_local, mir_w1, mir_w2,
                                  s_xB, s_mir, highway_w, s_h, s_hf1, w_hl, 0);
  k5ab<<<B * S, 128, 0, stream>>>(s_xB, adj, a_local + 4 * D,
                                  mir_w1 + (long)D * D, mir_w2 + (long)D * D,
                                  s_xA, s_mir, highway_w, s_h,
                                  s_hf1 /* x_dot */, w_hl, 1);
  k8_glu<<<B, 512, 0, stream>>>(s_hf2 /* h_global */, s_hf1 /* x_dot */, pos,
                                w_hl, w_mi, glu1, glu2, glu4, glu4b, w_s,
                                gate_w, w_zh);
  k9_scores<<<(NSC + 63) / 64, 256, 0, stream>>>(w_zh, emb, w_loss,
                                                 (float*)d_out);
}

// Round 12
// 733.518 us; speedup vs baseline: 1.2031x; 1.2031x over previous
//
#include <hip/hip_runtime.h>
#include <hip/hip_bf16.h>
#include <type_traits>

// CombineGraph forward. B=128,S=50,D=128,NODES=40000,SAMPLE=12,NNEI=8,HOP=2.
// Round 12: kG reverted to the measured-best R7 structure (128 thr, serial
// units) + register prefetch; emb pre-converted to bf16 in d_ws (halves
// gather lines) with a ws_size guard falling back to fp32 templates.

#define B 128
#define S 50
#define D 128
#define SAMPLE 12
#define NNEI 8
#define NODES 40000
#define NSC (NODES - 1)
#define LEAK 0.2f
#define TEMPV 0.5f
#define MUV 0.1f
#define NEG_BIG -3.0e38f

typedef const float* fpp;
typedef float* fpw;
typedef unsigned short u16;
typedef __attribute__((ext_vector_type(8))) short bfrag8;
typedef __attribute__((ext_vector_type(4))) float f32x4;

__device__ __forceinline__ float sigm(float x) { return 1.f / (1.f + __expf(-x)); }
__device__ __forceinline__ float tanh_f(float x) { return 1.f - 2.f / (__expf(2.f * x) + 1.f); }
__device__ __forceinline__ float leaky(float x) { return x >= 0.f ? x : LEAK * x; }
__device__ __forceinline__ u16 f2bf(float v) {
  __hip_bfloat16 h = __float2bfloat16(v);
  return *reinterpret_cast<u16*>(&h);
}
__device__ __forceinline__ float lde(const float* p, long i) { return p[i]; }
__device__ __forceinline__ float lde(const u16* p, long i) {
  union { unsigned int u; float f; } c;
  c.u = ((unsigned int)p[i]) << 16;
  return c.f;
}

// ---------------------------------------------------------------------------
// KPREP_EMB: emb fp32 -> bf16 copy in ws (4 elems/thread).
__global__ __launch_bounds__(256) void kprep_emb(fpp emb, u16* __restrict__ out) {
  long i = ((long)blockIdx.x * 256 + threadIdx.x) * 4;
  if (i + 3 >= (long)NODES * D) return;
  float4 v = *(const float4*)(emb + i);
  out[i + 0] = f2bf(v.x); out[i + 1] = f2bf(v.y);
  out[i + 2] = f2bf(v.z); out[i + 3] = f2bf(v.w);
}

// ---------------------------------------------------------------------------
// KPREP4: four weight tensors -> bf16 B-fragment order.
__global__ __launch_bounds__(256) void kprep4(fpp gw1, fpp gw3,
                                              u16* __restrict__ p1a,
                                              u16* __restrict__ p1b,
                                              u16* __restrict__ p3a,
                                              u16* __restrict__ p3b) {
  int i = blockIdx.x * 256 + threadIdx.x;
  fpp W; u16* dst; int KS;
  if (i < 16384)      { W = gw1;             dst = p1a; KS = 4; }
  else if (i < 32768) { W = gw1 + 129 * 128; dst = p1b; KS = 4; i -= 16384; }
  else if (i < 65536) { W = gw3;             dst = p3a; KS = 8; i -= 32768; }
  else                { W = gw3 + 256 * 128; dst = p3b; KS = 8; i -= 65536; }
  int e = i & 7;
  int lane = (i >> 3) & 63;
  int rest = i >> 9;
  int ks = rest % KS, nt = rest / KS;
  int k = ks * 32 + ((lane >> 4) << 3) + e;
  int n = (nt << 4) + (lane & 15);
  dst[i] = f2bf(W[(long)k * 128 + n]);
}

// ---------------------------------------------------------------------------
// K1: h = emb[inputs]; hf1/hf2 pools; attr gate. Block per (b,s), 128 thr.
template <typename ET>
__global__ __launch_bounds__(128) void k1_gather(
    const int* __restrict__ inputs, const int* __restrict__ as0,
    const int* __restrict__ as1, const int* __restrict__ ss0,
    const int* __restrict__ ss1, const ET* __restrict__ emb, fpp attr_w,
    fpw h, fpw hf1, fpw hf2, float* __restrict__ mi, fpw xA, fpw mir) {
  int bs = blockIdx.x;
  int d = threadIdx.x;
  __shared__ float h_s[D], hf1_s[D];
  int inp = inputs[bs];
  float hv = lde(emb, (long)inp * D + d);
  const int* lists[4] = {as0, as1, ss0, ss1};
  float p[4];
#pragma unroll
  for (int l = 0; l < 4; l++) {
    float sum = 0.f, cnt = 0.f;
    const int* L = lists[l] + (long)bs * NNEI;
#pragma unroll
    for (int n = 0; n < NNEI; n++) {
      int idx = L[n];
      if (idx != 0) { sum += lde(emb, (long)idx * D + d); cnt += 1.f; }
    }
    p[l] = sum / (cnt + 1e-8f);
  }
  float hf1v = 0.5f * (p[0] + p[1]);
  float hf2v = 0.5f * (p[2] + p[3]);
  h_s[d] = hv;
  hf1_s[d] = hf1v;
  __syncthreads();
  float acc = 0.f;
  for (int k = 0; k < D; k++)
    acc += h_s[k] * attr_w[(long)k * D + d] + hf1_s[k] * attr_w[(long)(D + k) * D + d];
  float g = sigm(acc);
  float hfv = g * hv + (1.f - g) * hf1v;
  long o = (long)bs * D + d;
  h[o] = hv; hf1[o] = hf1v; hf2[o] = hf2v; xA[o] = hv; mir[o] = hfv;
  if (d == 0) mi[bs] = (inp != 0) ? 1.f : 0.f;
}

// ---------------------------------------------------------------------------
// K2: sess[b,:] = sum_s emb[item[b,s]]*mi / sum_s mi
__global__ __launch_bounds__(128) void k2_sess(const int* __restrict__ inputs,
                                               const int* __restrict__ item,
                                               fpp emb, fpw sess) {
  int b = blockIdx.x;
  int d = threadIdx.x;
  float acc = 0.f, ms = 0.f;
  for (int s = 0; s < S; s++) {
    int inp = inputs[b * S + s];
    float m = (inp != 0) ? 1.f : 0.f;
    int it = item[b * S + s];
    acc += emb[(long)it * D + d] * m;
    ms += m;
  }
  sess[(long)b * D + d] = acc / ms;
}

// ---------------------------------------------------------------------------
// KG: 2-hop global branch — R7 structure (128 thr, 2 waves, serial units)
// + register prefetch of next unit's rows. Template on emb dtype.
template <typename ET>
__global__ __launch_bounds__(128) void kG_global(
    const int* __restrict__ inputs, const int* __restrict__ adj_all,
    fpp num, const ET* __restrict__ emb, fpp sess,
    fpp W1a, fpp W2a, fpp W1b, fpp W2b, fpp W3b,
    const u16* __restrict__ p1a, const u16* __restrict__ p1b,
    const u16* __restrict__ p3a, const u16* __restrict__ p3b,
    fpw hg) {
  int bs = blockIdx.x;
  int b = bs / S;
  int d = threadIdx.x;
  int lane = d & 63;
  int w = d >> 6;
  int q = lane >> 4;
  int mrow = lane & 15;

  __shared__ __align__(16) u16 nvs_l[16 * 136];
  __shared__ __align__(16) u16 svagg_l[16 * 264];
  __shared__ __align__(16) float ev_l[13 * 128];
  __shared__ __align__(16) float agg1_l[128];
  __shared__ float red_l[2][16];
  __shared__ float nw_l[16];

#pragma unroll
  for (int r = 12; r < 16; r++) {
    nvs_l[r * 136 + d] = 0;
    if (d < 8) nvs_l[r * 136 + 128 + d] = 0;
  }
#pragma unroll
  for (int r = 13; r < 16; r++) {
    svagg_l[r * 264 + d] = 0;
    svagg_l[r * 264 + 128 + d] = 0;
    if (d < 8) svagg_l[r * 264 + 256 + d] = 0;
  }

  float sess_d = sess[(long)b * D + d];
  int src0 = __builtin_amdgcn_readfirstlane(inputs[bs]);
  int n1[SAMPLE];
#pragma unroll
  for (int j = 0; j < SAMPLE; j++)
    n1[j] = __builtin_amdgcn_readfirstlane(adj_all[(long)src0 * SAMPLE + j]);
  svagg_l[0 * 264 + d] = f2bf(lde(emb, (long)src0 * D + d));

  float w2A[4], wlA[4], w2B[4], wlB[4];
#pragma unroll
  for (int nt = 0; nt < 4; nt++) {
    int col = (w * 4 + nt) * 16 + mrow;
    w2A[nt] = W2a[col];
    wlA[nt] = W1a[(long)D * D + col];
    w2B[nt] = W2b[col];
    wlB[nt] = W1b[(long)D * D + col];
  }

  // ---- Phase A: 13 hop-0 units, prefetch-pipelined ----------------------
  float pre[SAMPLE], pnw = 0.f;
  {
#pragma unroll
    for (int j = 0; j < SAMPLE; j++)
      pre[j] = lde(emb, (long)n1[j] * D + d);  // unit 0 rows (= adj_all[src0])
    if (d < SAMPLE) pnw = num[(long)src0 * SAMPLE + d];
  }
  for (int u = 0; u < 13; u++) {
    if (d < SAMPLE) nw_l[d] = pnw;
    float nvreg[SAMPLE];
#pragma unroll
    for (int j = 0; j < SAMPLE; j++) {
      nvreg[j] = pre[j];
      nvs_l[j * 136 + d] = f2bf(pre[j] * sess_d);
    }
    if (u == 0) {
#pragma unroll
      for (int j = 0; j < SAMPLE; j++)
        svagg_l[(1 + j) * 264 + d] = f2bf(nvreg[j]);
    }
    __syncthreads();  // staging visible
    // prefetch next unit's rows (overlap MFMA + epilogue below)
    if (u < 12) {
      int srcn = n1[u];  // next unit u+1 has src = n1[u]
#pragma unroll
      for (int j = 0; j < SAMPLE; j++) {
        int nj = __builtin_amdgcn_readfirstlane(adj_all[(long)srcn * SAMPLE + j]);
        pre[j] = lde(emb, (long)nj * D + d);
      }
      if (d < SAMPLE) pnw = num[(long)srcn * SAMPLE + d];
    }
    f32x4 acc[4];
#pragma unroll
    for (int nt = 0; nt < 4; nt++) acc[nt] = (f32x4){0.f, 0.f, 0.f, 0.f};
#pragma unroll
    for (int ks = 0; ks < 4; ks++) {
      bfrag8 a = *(const bfrag8*)(nvs_l + mrow * 136 + q * 8 + ks * 32);
      const u16* pb = p1a + (w * 16 + ks) * 512 + lane * 8;
#pragma unroll
      for (int nt = 0; nt < 4; nt++) {
        bfrag8 bb = *(const bfrag8*)(pb + nt * 2048);
        acc[nt] = __builtin_amdgcn_mfma_f32_16x16x32_bf16(a, bb, acc[nt], 0, 0, 0);
      }
    }
    float lp[4] = {0.f, 0.f, 0.f, 0.f};
    float nwq[4];
#pragma unroll
    for (int i = 0; i < 4; i++) nwq[i] = (q < 3) ? nw_l[q * 4 + i] : 0.f;
#pragma unroll
    for (int nt = 0; nt < 4; nt++)
#pragma unroll
      for (int i = 0; i < 4; i++)
        lp[i] += leaky(acc[nt][i] + nwq[i] * wlA[nt]) * w2A[nt];
#pragma unroll
    for (int off = 1; off <= 8; off <<= 1)
#pragma unroll
      for (int i = 0; i < 4; i++) lp[i] += __shfl_xor(lp[i], off, 64);
    if (mrow == 0 && q < 3) {
#pragma unroll
      for (int i = 0; i < 4; i++) red_l[w][q * 4 + i] = lp[i];
    }
    __syncthreads();
    float lg[SAMPLE];
#pragma unroll
    for (int j = 0; j < SAMPLE; j++) lg[j] = red_l[0][j] + red_l[1][j];
    float mx = lg[0];
#pragma unroll
    for (int j = 1; j < SAMPLE; j++) mx = fmaxf(mx, lg[j]);
    float se = 0.f;
#pragma unroll
    for (int j = 0; j < SAMPLE; j++) { lg[j] = __expf(lg[j] - mx); se += lg[j]; }
    float inv = 1.f / se;
    float aggd = 0.f;
#pragma unroll
    for (int j = 0; j < SAMPLE; j++) aggd += lg[j] * inv * nvreg[j];
    svagg_l[u * 264 + 128 + d] = f2bf(aggd);
  }
  __syncthreads();  // all svagg rows settled

  // ---- Phase B: [sv|agg] (13x256) @ W3a -> ev (tanh) --------------------
  {
    f32x4 accB[4];
#pragma unroll
    for (int nt = 0; nt < 4; nt++) accB[nt] = (f32x4){0.f, 0.f, 0.f, 0.f};
#pragma unroll
    for (int ks = 0; ks < 8; ks++) {
      bfrag8 a = *(const bfrag8*)(svagg_l + mrow * 264 + q * 8 + ks * 32);
      const u16* pb = p3a + (w * 32 + ks) * 512 + lane * 8;
#pragma unroll
      for (int nt = 0; nt < 4; nt++) {
        bfrag8 bb = *(const bfrag8*)(pb + nt * 4096);
        accB[nt] = __builtin_amdgcn_mfma_f32_16x16x32_bf16(a, bb, accB[nt], 0, 0, 0);
      }
    }
#pragma unroll
    for (int nt = 0; nt < 4; nt++) {
      int col = (w * 4 + nt) * 16 + mrow;
#pragma unroll
      for (int i = 0; i < 4; i++) {
        int u2 = q * 4 + i;
        if (u2 < 13) ev_l[u2 * 128 + col] = tanh_f(accB[nt][i]);
      }
    }
    __syncthreads();
  }

  // ---- Phase C: hop-1 unit ----------------------------------------------
  {
    float evreg[SAMPLE];
#pragma unroll
    for (int j = 0; j < SAMPLE; j++) {
      float e = ev_l[(1 + j) * 128 + d];
      evreg[j] = e;
      nvs_l[j * 136 + d] = f2bf(e * sess_d);
    }
    if (d < SAMPLE) nw_l[d] = num[(long)src0 * SAMPLE + d];
    __syncthreads();

    f32x4 acc[4];
#pragma unroll
    for (int nt = 0; nt < 4; nt++) acc[nt] = (f32x4){0.f, 0.f, 0.f, 0.f};
#pragma unroll
    for (int ks = 0; ks < 4; ks++) {
      bfrag8 a = *(const bfrag8*)(nvs_l + mrow * 136 + q * 8 + ks * 32);
      const u16* pb = p1b + (w * 16 + ks) * 512 + lane * 8;
#pragma unroll
      for (int nt = 0; nt < 4; nt++) {
        bfrag8 bb = *(const bfrag8*)(pb + nt * 2048);
        acc[nt] = __builtin_amdgcn_mfma_f32_16x16x32_bf16(a, bb, acc[nt], 0, 0, 0);
      }
    }
    float lp[4] = {0.f, 0.f, 0.f, 0.f};
    float nwq[4];
#pragma unroll
    for (int i = 0; i < 4; i++) nwq[i] = (q < 3) ? nw_l[q * 4 + i] : 0.f;
#pragma unroll
    for (int nt = 0; nt < 4; nt++)
#pragma unroll
      for (int i = 0; i < 4; i++)
        lp[i] += leaky(acc[nt][i] + nwq[i] * wlB[nt]) * w2B[nt];
#pragma unroll
    for (int off = 1; off <= 8; off <<= 1)
#pragma unroll
      for (int i = 0; i < 4; i++) lp[i] += __shfl_xor(lp[i], off, 64);
    if (mrow == 0 && q < 3) {
#pragma unroll
      for (int i = 0; i < 4; i++) red_l[w][q * 4 + i] = lp[i];
    }
    __syncthreads();

    float lg[SAMPLE];
#pragma unroll
    for (int j = 0; j < SAMPLE; j++) lg[j] = red_l[0][j] + red_l[1][j];
    float mx = lg[0];
#pragma unroll
    for (int j = 1; j < SAMPLE; j++) mx = fmaxf(mx, lg[j]);
    float se = 0.f;
#pragma unroll
    for (int j = 0; j < SAMPLE; j++) { lg[j] = __expf(lg[j] - mx); se += lg[j]; }
    float inv = 1.f / se;
    float agg1d = 0.f;
#pragma unroll
    for (int j = 0; j < SAMPLE; j++) agg1d += lg[j] * inv * evreg[j];
    agg1_l[d] = agg1d;
    __syncthreads();

    float accf = 0.f;
#pragma unroll 4
    for (int k4 = 0; k4 < 32; k4++) {
      float4 a4 = *(const float4*)&ev_l[4 * k4];
      float4 g4 = *(const float4*)&agg1_l[4 * k4];
      accf += a4.x * W3b[(4 * k4 + 0) * D + d] + a4.y * W3b[(4 * k4 + 1) * D + d] +
              a4.z * W3b[(4 * k4 + 2) * D + d] + a4.w * W3b[(4 * k4 + 3) * D + d] +
              g4.x * W3b[(D + 4 * k4 + 0) * D + d] + g4.y * W3b[(D + 4 * k4 + 1) * D + d] +
              g4.z * W3b[(D + 4 * k4 + 2) * D + d] + g4.w * W3b[(D + 4 * k4 + 3) * D + d];
    }
    hg[(long)bs * D + d] = tanh_f(accf);
  }
}

// ---------------------------------------------------------------------------
// K5AB: fused local-attention + mirror gate (+highway on fin=1). 128 thr.
__global__ __launch_bounds__(128) void k5ab(fpp x, const int* __restrict__ adj,
                                            fpp a_loc, fpp w1, fpp w2,
                                            fpw xout, fpw mir,
                                            fpp hw, fpp h, fpw x_dot,
                                            float* __restrict__ h_local,
                                            int fin) {
  int b = blockIdx.x / S;
  int row = blockIdx.x % S;
  int tid = threadIdx.x;
  __shared__ float xi_s[D];
  __shared__ float ak_s[4][D];
  __shared__ float alpha_s[S];
  __shared__ float part_s[4][2][64];
  long idx = ((long)b * S + row) * D + tid;
  xi_s[tid] = x[idx];
#pragma unroll
  for (int k = 0; k < 4; k++) ak_s[k][tid] = a_loc[(long)k * D + tid];
  __syncthreads();
  {
    int j = tid & 63, hf = tid >> 6;
    float a0 = 0.f, a1 = 0.f, a2 = 0.f, a3 = 0.f;
    if (j < S) {
      const float* xj = x + ((long)b * S + j) * D + hf * 64;
      int off = hf * 64;
      for (int dd = 0; dd < 64; dd++) {
        float prod = xi_s[off + dd] * xj[dd];
        a0 += prod * ak_s[0][off + dd];
        a1 += prod * ak_s[1][off + dd];
        a2 += prod * ak_s[2][off + dd];
        a3 += prod * ak_s[3][off + dd];
      }
    }
    part_s[0][hf][j] = a0; part_s[1][hf][j] = a1;
    part_s[2][hf][j] = a2; part_s[3][hf][j] = a3;
  }
  __syncthreads();
  if (tid < 64) {
    int j = tid;
    float att;
    if (j < S) {
      float acc0 = part_s[0][0][j] + part_s[0][1][j];
      float acc1 = part_s[1][0][j] + part_s[1][1][j];
      float acc2 = part_s[2][0][j] + part_s[2][1][j];
      float acc3 = part_s[3][0][j] + part_s[3][1][j];
      int av = adj[((long)b * S + row) * S + j];
      att = -9e15f;  // reference's own sentinel
      if (av == 1) att = leaky(acc0);
      else if (av == 2) att = leaky(acc1);
      else if (av == 3) att = leaky(acc2);
      else if (av == 4) att = leaky(acc3);
    } else {
      att = NEG_BIG;
    }
    float mx = att;
#pragma unroll
    for (int o = 32; o > 0; o >>= 1) mx = fmaxf(mx, __shfl_xor(mx, o, 64));
    float e = __expf(att - mx);
    float ssum = e;
#pragma unroll
    for (int o = 32; o > 0; o >>= 1) ssum += __shfl_xor(ssum, o, 64);
    if (j < S) alpha_s[j] = e / ssum;
  }
  __syncthreads();
  float xn = 0.f;
  for (int j = 0; j < S; j++) xn += alpha_s[j] * x[((long)b * S + j) * D + tid];
  float mv = mir[idx];
  ak_s[0][tid] = xn;
  ak_s[1][tid] = mv;
  __syncthreads();
  float a2m = 0.f;
  for (int k = 0; k < D; k++)
    a2m += ak_s[0][k] * w1[(long)k * D + tid] + ak_s[1][k] * w2[(long)k * D + tid];
  float g = sigm(a2m);
  float xg = g * xn + (1.f - g) * mv;
  if (!fin) {
    xout[idx] = xg;
    mir[idx] = g * mv + (1.f - g) * xn;
    return;
  }
  float hv = h[idx];
  ak_s[2][tid] = hv;
  ak_s[3][tid] = xg;
  __syncthreads();
  float a3m = 0.f;
  for (int k = 0; k < D; k++)
    a3m += ak_s[2][k] * hw[(long)k * D + tid] + ak_s[3][k] * hw[(long)(D + k) * D + tid];
  float gh = sigm(a3m);
  float xd = gh * hv + (1.f - gh) * xg;
  x_dot[idx] = xd;
  if (row == S - 1) h_local[(long)b * D + tid] = xd;
}

// ---------------------------------------------------------------------------
// K7: simi loss. Block per (b,i), 128 threads (split-dot). atomicAdd to ws.
__global__ __launch_bounds__(128) void k7_simi(fpp hf1, fpp hf2,
                                               const int* __restrict__ simi_mask,
                                               float* __restrict__ loss) {
  int b = blockIdx.x / S;
  int i = blockIdx.x % S;
  int t = threadIdx.x;
  __shared__ float hi_s[D];
  __shared__ float part_s[2][64];
  hi_s[t] = hf1[((long)b * S + i) * D + t];
  __syncthreads();
  {
    int j = t & 63, hf = t >> 6;
    float acc = 0.f;
    if (j < S) {
      const float* r = hf2 + ((long)b * S + j) * D + hf * 64;
      int off = hf * 64;
      for (int dd = 0; dd < 64; dd++) acc += hi_s[off + dd] * r[dd];
    }
    part_s[hf][j] = acc;
  }
  __syncthreads();
  if (t < 64) {
    int j = t;
    float sim = (j < S) ? (part_s[0][j] + part_s[1][j]) * (1.0f / TEMPV) : NEG_BIG;
    float mx = sim;
#pragma unroll
    for (int o = 32; o > 0; o >>= 1) mx = fmaxf(mx, __shfl_xor(mx, o, 64));
    float e = __expf(sim - mx);
    float ssum = e;
#pragma unroll
    for (int o = 32; o > 0; o >>= 1) ssum += __shfl_xor(ssum, o, 64);
    float contrib = 0.f;
    if (j < S) {
      float p = e / ssum;
      float l = -__logf(p + 1e-8f);
      if (simi_mask[((long)b * S + i) * S + j] == 1) contrib = l;
    }
#pragma unroll
    for (int o = 32; o > 0; o >>= 1) contrib += __shfl_xor(contrib, o, 64);
    if (j == 0) atomicAdd(loss, contrib);
  }
}

// ---------------------------------------------------------------------------
// K8: GLU epilogue per batch, 512 threads = 4 s-groups (serial 50 -> 13).
__global__ __launch_bounds__(512) void k8_glu(
    fpp hg, fpp x_dot, fpp pos, fpp h_local, const float* __restrict__ mi,
    fpp glu1, fpp glu2, fpp glu4, fpp glu4b, fpp w_s, fpp gate_w, fpw zh) {
  int b = blockIdx.x;
  int t = threadIdx.x;
  int d = t & 127;
  int g = t >> 7;   // s-group 0..3
  __shared__ float hs_s[D], hl_s[D];
  __shared__ float hp_g[4][D], part[4][D], zg_g[4][D];
  __shared__ float red2[4][2];
  float msf = 0.f;
  for (int s = 0; s < S; s++) msf += mi[b * S + s];
  float hsacc = 0.f;
  for (int s = g * 13; s < min(S, g * 13 + 13); s++)
    hsacc += hg[((long)b * S + s) * D + d] * mi[b * S + s];
  part[g][d] = hsacc;
  if (g == 1) hl_s[d] = h_local[(long)b * D + d];
  __syncthreads();
  if (g == 0) hs_s[d] = (part[0][d] + part[1][d] + part[2][d] + part[3][d]) / msf;
  __syncthreads();
  float c = glu4b[d];
  for (int k = 0; k < D; k++)
    c += hs_s[k] * glu2[(long)k * D + d] + hl_s[k] * glu4[(long)k * D + d];
  float wsd = w_s[d];
  float zg = 0.f;
  for (int it = 0; it < 13; it++) {
    int s = g * 13 + it;
    bool act = s < S;
    float hp = 0.f;
    if (act) {
      hp = x_dot[((long)b * S + s) * D + d] + pos[(long)s * D + d];
      hp_g[g][d] = hp;
    }
    __syncthreads();
    if (act) {
      float acc = c;
      for (int k = 0; k < D; k++) acc += hp_g[g][k] * glu1[(long)k * D + d];
      float v = sigm(acc) * wsd;
#pragma unroll
      for (int o = 32; o > 0; o >>= 1) v += __shfl_down(v, o, 64);
      if ((t & 63) == 0) red2[g][(t >> 6) & 1] = v;
    }
    __syncthreads();
    if (act) {
      float beta = (red2[g][0] + red2[g][1]) * mi[b * S + s];
      zg += beta * hp;
    }
    __syncthreads();
  }
  zg_g[g][d] = zg;
  __syncthreads();
  if (g == 0) {
    float zgf = zg_g[0][d] + zg_g[1][d] + zg_g[2][d] + zg_g[3][d];
    hp_g[0][d] = zgf;
  }
  __syncthreads();
  if (g == 0) {
    float zgf = hp_g[0][d];
    float acc = 0.f;
    for (int k = 0; k < D; k++)
      acc += hp_g[0][k] * gate_w[(long)k * D + d] +
             hl_s[k] * gate_w[(long)(D + k) * D + d];
    float gf = sigm(acc) * MUV;
    zh[(long)b * D + d] = gf * hl_s[d] + (1.f - gf) * zgf;
  }
}

// ---------------------------------------------------------------------------
// K9: scores = zh(128x128) @ emb[1:]^T via bf16 MFMA. Template on emb dtype
// (bf16 path loads B-frags directly, no converts).
template <typename ET>
__global__ __launch_bounds__(256) void k9_scores(fpp zh, const ET* __restrict__ emb,
                                                 fpp loss, float* __restrict__ out) {
  int t = threadIdx.x;
  if (blockIdx.x == 0 && t == 0) out[0] = loss[0] * (1.0f / (float)B);
  int lane = t & 63;
  int w = t >> 6;
  int q = lane >> 4;
  int mrow = lane & 15;
  long n = (long)blockIdx.x * 64 + w * 16 + mrow;
  bool valid = n < NSC;
  long nrow = valid ? (n + 1) : 1;
  bfrag8 bfr[4];
#pragma unroll
  for (int ks = 0; ks < 4; ks++) {
    if constexpr (sizeof(ET) == 2) {
      bfr[ks] = *(const bfrag8*)(const void*)(emb + nrow * D + ks * 32 + q * 8);
    } else {
      const float* src = (const float*)(emb + nrow * D + ks * 32 + q * 8);
      float4 lo = *(const float4*)src;
      float4 hi = *(const float4*)(src + 4);
      bfrag8 bb;
      bb[0] = (short)f2bf(lo.x); bb[1] = (short)f2bf(lo.y);
      bb[2] = (short)f2bf(lo.z); bb[3] = (short)f2bf(lo.w);
      bb[4] = (short)f2bf(hi.x); bb[5] = (short)f2bf(hi.y);
      bb[6] = (short)f2bf(hi.z); bb[7] = (short)f2bf(hi.w);
      bfr[ks] = bb;
    }
  }
#pragma unroll
  for (int mt = 0; mt < 8; mt++) {
    f32x4 acc = (f32x4){0.f, 0.f, 0.f, 0.f};
#pragma unroll
    for (int ks = 0; ks < 4; ks++) {
      const float* za = zh + (long)(mt * 16 + mrow) * D + ks * 32 + q * 8;
      float4 lo = *(const float4*)za;
      float4 hi = *(const float4*)(za + 4);
      bfrag8 a;
      a[0] = (short)f2bf(lo.x); a[1] = (short)f2bf(lo.y);
      a[2] = (short)f2bf(lo.z); a[3] = (short)f2bf(lo.w);
      a[4] = (short)f2bf(hi.x); a[5] = (short)f2bf(hi.y);
      a[6] = (short)f2bf(hi.z); a[7] = (short)f2bf(hi.w);
      acc = __builtin_amdgcn_mfma_f32_16x16x32_bf16(a, bfr[ks], acc, 0, 0, 0);
    }
    if (valid) {
#pragma unroll
      for (int i = 0; i < 4; i++) {
        int m = mt * 16 + q * 4 + i;
        out[1 + (long)m * NSC + n] = acc[i];
      }
    }
  }
}

// ---------------------------------------------------------------------------
extern "C" void kernel_launch(void* const* d_in, const int* in_sizes, int n_in,
                              void* d_out, int out_size, void* d_ws, size_t ws_size,
                              hipStream_t stream) {
  (void)in_sizes; (void)n_in; (void)out_size;
  const int* inputs = (const int*)d_in[0];
  const int* adj = (const int*)d_in[1];
  const int* item = (const int*)d_in[2];
  const int* simi_mask = (const int*)d_in[3];
  const int* as0 = (const int*)d_in[4];
  const int* as1 = (const int*)d_in[5];
  const int* ss0 = (const int*)d_in[6];
  const int* ss1 = (const int*)d_in[7];
  // d_in[8]: last_item_mask — structurally [:, -1]; hardcoded in k5ab(fin).
  const int* adj_all = (const int*)d_in[9];
  fpp num = (fpp)d_in[10];
  fpp emb = (fpp)d_in[11];
  fpp pos = (fpp)d_in[12];
  fpp a_local = (fpp)d_in[13];
  fpp mir_w1 = (fpp)d_in[14];
  fpp mir_w2 = (fpp)d_in[15];
  fpp gw1 = (fpp)d_in[16];
  fpp gw2 = (fpp)d_in[17];
  fpp gw3 = (fpp)d_in[18];
  fpp attr_w = (fpp)d_in[19];
  fpp highway_w = (fpp)d_in[20];
  fpp glu1 = (fpp)d_in[21];
  fpp glu2 = (fpp)d_in[22];
  fpp glu4 = (fpp)d_in[23];
  fpp glu4b = (fpp)d_in[24];
  fpp w_s = (fpp)d_in[25];
  fpp gate_w = (fpp)d_in[26];

  // fp32 scratch inside d_out: 6 * 819200 = 4,915,200 elts <= 5,119,873.
  float* ob = (float*)d_out;
  constexpr long BSD_ = (long)B * S * D;  // 819200
  fpw s_h = ob + 0 * BSD_;
  fpw s_hf1 = ob + 1 * BSD_;  // later x_dot
  fpw s_hf2 = ob + 2 * BSD_;  // later h_global
  fpw s_mir = ob + 3 * BSD_;
  fpw s_xA = ob + 4 * BSD_;
  fpw s_xB = ob + 5 * BSD_;

  // d_ws layout: small fp32 state (loss at ws[0]) .. float 72000; prepped
  // weight frags (196,608 B) at byte 288,000; bf16 emb (10.24 MB, guarded)
  // at byte 491,520.
  float* ws = (float*)d_ws;
  float* w_loss = ws + 0;
  float* w_mi = ws + 16;                // B*S
  float* w_sess = w_mi + (long)B * S;   // B*D
  float* w_hl = w_sess + (long)B * D;   // B*D
  float* w_zh = w_hl + (long)B * D;     // B*D
  u16* p1a = (u16*)(ws + 72000);
  u16* p1b = (u16*)(ws + 72000 + 8192);
  u16* p3a = (u16*)(ws + 72000 + 16384);
  u16* p3b = (u16*)(ws + 72000 + 32768);
  u16* embbf = (u16*)((char*)d_ws + 491520);
  bool useBF = ws_size >= (size_t)12 * 1024 * 1024;

  hipMemsetAsync((void*)w_loss, 0, sizeof(float), stream);

  kprep4<<<384, 256, 0, stream>>>(gw1, gw3, p1a, p1b, p3a, p3b);
  if (useBF)
    kprep_emb<<<(NODES * D / 4 + 255) / 256, 256, 0, stream>>>(emb, embbf);

  if (useBF)
    k1_gather<u16><<<B * S, 128, 0, stream>>>(inputs, as0, as1, ss0, ss1,
                                              embbf, attr_w, s_h, s_hf1, s_hf2,
                                              w_mi, s_xA, s_mir);
  else
    k1_gather<float><<<B * S, 128, 0, stream>>>(inputs, as0, as1, ss0, ss1,
                                                emb, attr_w, s_h, s_hf1, s_hf2,
                                                w_mi, s_xA, s_mir);
  // k7 consumes hf1/hf2 before kG reuses the hf2 slot as h_global.
  k7_simi<<<B * S, 128, 0, stream>>>(s_hf1, s_hf2, simi_mask, w_loss);
  k2_sess<<<B, 128, 0, stream>>>(inputs, item, emb, w_sess);
  if (useBF)
    kG_global<u16><<<B * S, 128, 0, stream>>>(inputs, adj_all, num, embbf,
                                              w_sess, gw1, gw2,
                                              gw1 + 129 * 128, gw2 + 128,
                                              gw3 + 256 * 128, p1a, p1b, p3a,
                                              p3b, s_hf2 /* h_global */);
  else
    kG_global<float><<<B * S, 128, 0, stream>>>(inputs, adj_all, num, emb,
                                                w_sess, gw1, gw2,
                                                gw1 + 129 * 128, gw2 + 128,
                                                gw3 + 256 * 128, p1a, p1b, p3a,
                                                p3b, s_hf2 /* h_global */);
  k5ab<<<B * S, 128, 0, stream>>>(s_xA, adj, a_local, mir_w1, mir_w2,
                                  s_xB, s_mir, highway_w, s_h, s_hf1, w_hl, 0);
  k5ab<<<B * S, 128, 0, stream>>>(s_xB, adj, a_local + 4 * D,
                                  mir_w1 + (long)D * D, mir_w2 + (long)D * D,
                                  s_xA, s_mir, highway_w, s_h,
                                  s_hf1 /* x_dot */, w_hl, 1);
  k8_glu<<<B, 512, 0, stream>>>(s_hf2 /* h_global */, s_hf1 /* x_dot */, pos,
                                w_hl, w_mi, glu1, glu2, glu4, glu4b, w_s,
                                gate_w, w_zh);
  if (useBF)
    k9_scores<u16><<<(NSC + 63) / 64, 256, 0, stream>>>(w_zh, embbf, w_loss,
                                                        (float*)d_out);
  else
    k9_scores<float><<<(NSC + 63) / 64, 256, 0, stream>>>(w_zh, emb, w_loss,
                                                          (float*)d_out);
}